// Round 1
// baseline (428.081 us; speedup 1.0000x reference)
//
#include <hip/hip_runtime.h>
#include <math.h>

#define BB 4
#define NN 512
#define EE 128
#define NODE_F 16
#define EDGE_F 8
#define LL 3

// tanh(x) given targ = 2*log2(e)*x
__device__ __forceinline__ float tanh_scaled(float targ) {
    float ex = __builtin_amdgcn_exp2f(targ);
    float r  = __builtin_amdgcn_rcpf(ex + 1.0f);
    return fmaf(-2.0f, r, 1.0f);   // 1 - 2/(exp(2x)+1); saturates to +/-1
}

__global__ __launch_bounds__(128) void k_rows(
    const float* __restrict__ nf,          // B,N,16
    const float* __restrict__ ef,          // B,N,N,8
    const float* __restrict__ W,           // B,N,N
    const int*   __restrict__ assigned,    // B,N
    const int*   __restrict__ open_group,  // B,N
    const int*   __restrict__ action_mask, // B,N
    const float* __restrict__ build_limit, // B,3
    const float* __restrict__ open_group_size, // B,3
    const float* __restrict__ embed_w,     // 22,128
    const float* __restrict__ embed_b,     // 128
    const float* __restrict__ node_w,      // L,128,128
    const float* __restrict__ edge_w,      // L,8,128
    const float* __restrict__ weight_w,    // L,128
    const float* __restrict__ out_w,       // L,128,128
    const float* __restrict__ out_b,       // L,128
    float* __restrict__ hout)              // B*N,128
{
    const int i   = blockIdx.x;
    const int b   = blockIdx.y;
    const int e   = threadIdx.x;
    const int row = b * NN + i;

    __shared__ float sh[EE];    // reused: h then agg (per layer)
    __shared__ float xsh[24];   // the 22 input features of this row

    // ---- build x = [node_features(16), assigned, open, mask, ratio(3)] ----
    if (e < NODE_F) {
        xsh[e] = nf[row * NODE_F + e];
    } else if (e == 16) {
        xsh[16] = assigned[row] ? 1.0f : 0.0f;
    } else if (e == 17) {
        xsh[17] = open_group[row] ? 1.0f : 0.0f;
    } else if (e == 18) {
        xsh[18] = action_mask[row] ? 1.0f : 0.0f;
    } else if (e < 22) {
        int k = e - 19;
        xsh[e] = open_group_size[b * 3 + k] / fmaxf(build_limit[b * 3 + k], 1e-6f);
    }
    __syncthreads();

    // ---- h0 = x @ embed_w + embed_b ----
    float h = embed_b[e];
    #pragma unroll
    for (int k = 0; k < 22; ++k)
        h = fmaf(xsh[k], embed_w[k * EE + e], h);

    const float c = 2.8853900817779268f;   // 2*log2(e), folded into tanh arg

    const float* efrow = ef + (size_t)row * NN * EDGE_F;
    const float* Wrow  = W  + (size_t)row * NN;

    for (int l = 0; l < LL; ++l) {
        __syncthreads();
        sh[e] = h;
        __syncthreads();

        // hi = c * (h @ node_w[l])
        const float* nw = node_w + l * EE * EE;
        float hi = 0.0f;
        #pragma unroll 8
        for (int k = 0; k < EE; ++k)
            hi = fmaf(sh[k], nw[k * EE + e], hi);
        hi *= c;

        // per-layer per-channel constants (pre-scaled by c)
        const float* ew = edge_w + l * EDGE_F * EE;
        float we0 = c * ew[0 * EE + e];
        float we1 = c * ew[1 * EE + e];
        float we2 = c * ew[2 * EE + e];
        float we3 = c * ew[3 * EE + e];
        float we4 = c * ew[4 * EE + e];
        float we5 = c * ew[5 * EE + e];
        float we6 = c * ew[6 * EE + e];
        float we7 = c * ew[7 * EE + e];
        float wl  = c * weight_w[l * EE + e];

        // ---- the big j loop: agg_e = sum_j tanh(hi + ef.We + W*wl) ----
        float agg = 0.0f;
        #pragma unroll 4
        for (int j = 0; j < NN; ++j) {
            const float* er = efrow + j * EDGE_F;   // lane-uniform -> s_load
            float wj = Wrow[j];                     // lane-uniform -> s_load
            float t = hi;
            t = fmaf(er[0], we0, t);
            t = fmaf(er[1], we1, t);
            t = fmaf(er[2], we2, t);
            t = fmaf(er[3], we3, t);
            t = fmaf(er[4], we4, t);
            t = fmaf(er[5], we5, t);
            t = fmaf(er[6], we6, t);
            t = fmaf(wj,    wl,  t);
            t = fmaf(er[7], we7, t);
            agg += tanh_scaled(t);
        }
        agg *= (1.0f / NN);

        __syncthreads();
        sh[e] = agg;
        __syncthreads();

        // h = h + agg @ out_w[l] + out_b[l]
        const float* ow = out_w + l * EE * EE;
        float acc = h + out_b[l * EE + e];
        #pragma unroll 8
        for (int k = 0; k < EE; ++k)
            acc = fmaf(sh[k], ow[k * EE + e], acc);
        h = acc;
    }

    hout[(size_t)row * EE + e] = h;
}

__global__ __launch_bounds__(128) void k_ctx(
    const float* __restrict__ hbuf,        // B*N,128
    const int*   __restrict__ open_group,  // B,N
    const float* __restrict__ context_w,   // 128,128
    const float* __restrict__ key_w,       // 128,128
    float* __restrict__ qk)                // B,128  (= key_w @ query)
{
    const int b = blockIdx.x;
    const int e = threadIdx.x;
    __shared__ float sh[EE];

    const float* hb = hbuf + (size_t)b * NN * EE;

    float gm  = 0.0f;
    float cnt = 0.0f;
    for (int n = 0; n < NN; ++n) {
        if (open_group[b * NN + n]) {   // uniform branch
            gm  += hb[n * EE + e];
            cnt += 1.0f;
        }
    }
    float context = (cnt > 0.0f) ? (gm / fmaxf(cnt, 1.0f)) : hb[e]; // hb[e] = h[b,0,e]
    sh[e] = context;
    __syncthreads();

    float q = 0.0f;
    #pragma unroll 8
    for (int k = 0; k < EE; ++k)
        q = fmaf(sh[k], context_w[k * EE + e], q);
    __syncthreads();
    sh[e] = q;
    __syncthreads();

    // qk[k] = sum_e key_w[k,e] * q[e]   (thread index acts as k)
    float acc = 0.0f;
    const float* kr = key_w + e * EE;
    #pragma unroll 8
    for (int k = 0; k < EE; ++k)
        acc = fmaf(kr[k], sh[k], acc);
    qk[b * EE + e] = acc;
}

__global__ __launch_bounds__(64) void k_logits(
    const float* __restrict__ hbuf,        // B*N,128
    const float* __restrict__ qk,          // B,128
    const int*   __restrict__ action_mask, // B,N
    const float* __restrict__ logit_bias,  // 1
    float* __restrict__ out)               // B,N
{
    const int row  = blockIdx.x;       // b*N + n
    const int b    = row >> 9;
    const int lane = threadIdx.x;

    const float* hr = hbuf + (size_t)row * EE;
    const float* qb = qk + b * EE;

    float p = hr[lane] * qb[lane] + hr[lane + 64] * qb[lane + 64];
    #pragma unroll
    for (int off = 32; off; off >>= 1)
        p += __shfl_down(p, off);

    if (lane == 0) {
        float v = p * 0.08838834764831845f + logit_bias[0];  // /sqrt(128)
        out[row] = action_mask[row] ? v : -1000000000.0f;
    }
}

extern "C" void kernel_launch(void* const* d_in, const int* in_sizes, int n_in,
                              void* d_out, int out_size, void* d_ws, size_t ws_size,
                              hipStream_t stream) {
    const float* nf         = (const float*)d_in[0];
    const float* ef         = (const float*)d_in[1];
    const float* W          = (const float*)d_in[2];
    const int*   assigned   = (const int*)d_in[3];
    const int*   open_group = (const int*)d_in[4];
    const int*   action_mask= (const int*)d_in[5];
    const float* build_limit= (const float*)d_in[6];
    const float* og_size    = (const float*)d_in[7];
    const float* embed_w    = (const float*)d_in[8];
    const float* embed_b    = (const float*)d_in[9];
    const float* node_w     = (const float*)d_in[10];
    const float* edge_w     = (const float*)d_in[11];
    const float* weight_w   = (const float*)d_in[12];
    const float* out_w      = (const float*)d_in[13];
    const float* out_b      = (const float*)d_in[14];
    const float* context_w  = (const float*)d_in[15];
    const float* key_w      = (const float*)d_in[16];
    const float* logit_bias = (const float*)d_in[17];

    float* hbuf = (float*)d_ws;                       // B*N*E floats = 1 MB
    float* qk   = hbuf + (size_t)BB * NN * EE;        // B*E floats

    dim3 grid_rows(NN, BB, 1);
    k_rows<<<grid_rows, 128, 0, stream>>>(nf, ef, W, assigned, open_group,
        action_mask, build_limit, og_size, embed_w, embed_b, node_w, edge_w,
        weight_w, out_w, out_b, hbuf);

    k_ctx<<<BB, 128, 0, stream>>>(hbuf, open_group, context_w, key_w, qk);

    k_logits<<<BB * NN, 64, 0, stream>>>(hbuf, qk, action_mask, logit_bias,
        (float*)d_out);
}

// Round 2
// 353.640 us; speedup vs baseline: 1.2105x; 1.2105x over previous
//
#include <hip/hip_runtime.h>
#include <math.h>

#define BB 4
#define NN 512
#define EE 128
#define NODE_F 16
#define EDGE_F 8
#define LL 3

__global__ __launch_bounds__(512) void k_rows(
    const float* __restrict__ nf,          // B,N,16
    const float* __restrict__ ef,          // B,N,N,8
    const float* __restrict__ W,           // B,N,N
    const int*   __restrict__ assigned,    // B,N
    const int*   __restrict__ open_group,  // B,N
    const int*   __restrict__ action_mask, // B,N
    const float* __restrict__ build_limit, // B,3
    const float* __restrict__ open_group_size, // B,3
    const float* __restrict__ embed_w,     // 22,128
    const float* __restrict__ embed_b,     // 128
    const float* __restrict__ node_w,      // L,128,128
    const float* __restrict__ edge_w,      // L,8,128
    const float* __restrict__ weight_w,    // L,128
    const float* __restrict__ out_w,       // L,128,128
    const float* __restrict__ out_b,       // L,128
    float* __restrict__ hout)              // B*N,128
{
    const int i   = blockIdx.x;
    const int b   = blockIdx.y;
    const int t   = threadIdx.x;
    const int e   = t & 127;
    const int js  = t >> 7;          // 0..3, owns j in [js*128, js*128+128)
    const int row = b * NN + i;

    __shared__ __align__(16) float efsh[NN * EDGE_F]; // 16 KB, layer-invariant
    __shared__ float wsh[NN];                         // 2 KB
    __shared__ float hsh[EE];
    __shared__ float aggsh[4][EE];
    __shared__ float xsh[24];

    // ---- stage ef row + W row into LDS (coalesced float4) ----
    {
        const float4* ef4 = (const float4*)(ef + (size_t)row * NN * EDGE_F);
        float4* es4 = (float4*)efsh;
        es4[t]       = ef4[t];
        es4[t + 512] = ef4[t + 512];
        wsh[t & 511] = W[(size_t)row * NN + (t & 511)]; // each j written twice, benign
    }

    // ---- x = [node_features(16), assigned, open, mask, ratio(3)] ----
    if (t < NODE_F) {
        xsh[t] = nf[row * NODE_F + t];
    } else if (t == 16) {
        xsh[16] = assigned[row] ? 1.0f : 0.0f;
    } else if (t == 17) {
        xsh[17] = open_group[row] ? 1.0f : 0.0f;
    } else if (t == 18) {
        xsh[18] = action_mask[row] ? 1.0f : 0.0f;
    } else if (t < 22) {
        int k = t - 19;
        xsh[t] = open_group_size[b * 3 + k] / fmaxf(build_limit[b * 3 + k], 1e-6f);
    }
    __syncthreads();

    // ---- h0 = x @ embed_w + embed_b (by jslot 0 only) ----
    if (t < EE) {
        float h0 = embed_b[e];
        #pragma unroll
        for (int k = 0; k < 22; ++k)
            h0 = fmaf(xsh[k], embed_w[k * EE + e], h0);
        hsh[e] = h0;
    }
    __syncthreads();

    const float c = 2.8853900817779268f;   // 2*log2(e) folded into tanh arg
    const int j0 = js * 128;
    float hnew = 0.0f;

    for (int l = 0; l < LL; ++l) {
        // hi = c * (h @ node_w[l])  -- redundant across jslots
        const float* nw = node_w + l * EE * EE + e;
        float hi = 0.0f;
        #pragma unroll 8
        for (int k = 0; k < EE; ++k)
            hi = fmaf(hsh[k], nw[k * EE], hi);
        hi *= c;

        const float* ew = edge_w + l * EDGE_F * EE + e;
        const float we0 = c * ew[0 * EE];
        const float we1 = c * ew[1 * EE];
        const float we2 = c * ew[2 * EE];
        const float we3 = c * ew[3 * EE];
        const float we4 = c * ew[4 * EE];
        const float we5 = c * ew[5 * EE];
        const float we6 = c * ew[6 * EE];
        const float we7 = c * ew[7 * EE];
        const float wl  = c * weight_w[l * EE + e];

        // ---- 128 j's per slot: rsum = sum rcp(exp(2x)+1); tanh = 1-2r ----
        float rsum = 0.0f;
        #pragma unroll 4
        for (int jj = 0; jj < 128; ++jj) {
            const int j = j0 + jj;
            const float4 ea = *(const float4*)&efsh[j * 8];
            const float4 eb = *(const float4*)&efsh[j * 8 + 4];
            const float wj = wsh[j];
            float t0 = fmaf(ea.x, we0, hi);
            t0 = fmaf(ea.y, we1, t0);
            t0 = fmaf(ea.z, we2, t0);
            t0 = fmaf(ea.w, we3, t0);
            float t1 = fmaf(eb.y, we5, eb.x * we4);
            t1 = fmaf(eb.z, we6, t1);
            t1 = fmaf(eb.w, we7, t1);
            t1 = fmaf(wj, wl, t1);
            float ex = __builtin_amdgcn_exp2f(t0 + t1);
            rsum += __builtin_amdgcn_rcpf(ex + 1.0f);
        }
        aggsh[js][e] = rsum;
        __syncthreads();

        // agg_mean[e] = 1 - (sum of all r)/256
        if (js == 0)
            aggsh[0][e] = 1.0f - (aggsh[0][e] + aggsh[1][e] + aggsh[2][e] + aggsh[3][e])
                                 * (1.0f / 256.0f);
        __syncthreads();

        // h = h + agg @ out_w[l] + out_b[l]  -- redundant across jslots
        const float* ow = out_w + l * EE * EE + e;
        hnew = hsh[e] + out_b[l * EE + e];
        #pragma unroll 8
        for (int k = 0; k < EE; ++k)
            hnew = fmaf(aggsh[0][k], ow[k * EE], hnew);
        __syncthreads();          // everyone done reading hsh / aggsh
        if (js == 0) hsh[e] = hnew;
        __syncthreads();          // new h visible
    }

    if (t < EE) hout[(size_t)row * EE + e] = hnew;
}

__global__ __launch_bounds__(512) void k_ctx(
    const float* __restrict__ hbuf,        // B*N,128
    const int*   __restrict__ open_group,  // B,N
    const float* __restrict__ context_w,   // 128,128
    const float* __restrict__ key_w,       // 128,128
    float* __restrict__ qk)                // B,128  (= key_w @ query)
{
    const int b = blockIdx.x;
    const int t = threadIdx.x;
    const int e = t & 127;
    const int s = t >> 7;

    __shared__ float gmsh[4][EE];
    __shared__ float cntsh[4];
    __shared__ float csh[EE];
    __shared__ float qsh[EE];

    const float* hb = hbuf + (size_t)b * NN * EE;

    // masked sum over n, 4-way split, branch-free
    float gm = 0.0f, cnt = 0.0f;
    const int n0 = s * 128;
    #pragma unroll 4
    for (int u = 0; u < 128; ++u) {
        const int n = n0 + u;
        const float m = (float)open_group[b * NN + n];
        gm = fmaf(m, hb[(size_t)n * EE + e], gm);
        cnt += m;
    }
    gmsh[s][e] = gm;
    if (e == 0) cntsh[s] = cnt;
    __syncthreads();

    if (s == 0) {
        const float ca = cntsh[0] + cntsh[1] + cntsh[2] + cntsh[3];
        const float ga = gmsh[0][e] + gmsh[1][e] + gmsh[2][e] + gmsh[3][e];
        csh[e] = (ca > 0.0f) ? (ga / fmaxf(ca, 1.0f)) : hb[e];  // hb[e]=h[b,0,e]
    }
    __syncthreads();

    float q = 0.0f;
    if (s == 0) {
        #pragma unroll 8
        for (int k = 0; k < EE; ++k)
            q = fmaf(csh[k], context_w[k * EE + e], q);
    }
    __syncthreads();
    if (s == 0) qsh[e] = q;
    __syncthreads();

    if (s == 0) {
        float acc = 0.0f;
        const float* kr = key_w + e * EE;
        #pragma unroll 8
        for (int k = 0; k < EE; ++k)
            acc = fmaf(kr[k], qsh[k], acc);
        qk[b * EE + e] = acc;
    }
}

__global__ __launch_bounds__(64) void k_logits(
    const float* __restrict__ hbuf,        // B*N,128
    const float* __restrict__ qk,          // B,128
    const int*   __restrict__ action_mask, // B,N
    const float* __restrict__ logit_bias,  // 1
    float* __restrict__ out)               // B,N
{
    const int row  = blockIdx.x;       // b*N + n
    const int b    = row >> 9;
    const int lane = threadIdx.x;

    const float* hr = hbuf + (size_t)row * EE;
    const float* qb = qk + b * EE;

    float p = hr[lane] * qb[lane] + hr[lane + 64] * qb[lane + 64];
    #pragma unroll
    for (int off = 32; off; off >>= 1)
        p += __shfl_down(p, off);

    if (lane == 0) {
        float v = p * 0.08838834764831845f + logit_bias[0];  // /sqrt(128)
        out[row] = action_mask[row] ? v : -1000000000.0f;
    }
}

extern "C" void kernel_launch(void* const* d_in, const int* in_sizes, int n_in,
                              void* d_out, int out_size, void* d_ws, size_t ws_size,
                              hipStream_t stream) {
    const float* nf         = (const float*)d_in[0];
    const float* ef         = (const float*)d_in[1];
    const float* W          = (const float*)d_in[2];
    const int*   assigned   = (const int*)d_in[3];
    const int*   open_group = (const int*)d_in[4];
    const int*   action_mask= (const int*)d_in[5];
    const float* build_limit= (const float*)d_in[6];
    const float* og_size    = (const float*)d_in[7];
    const float* embed_w    = (const float*)d_in[8];
    const float* embed_b    = (const float*)d_in[9];
    const float* node_w     = (const float*)d_in[10];
    const float* edge_w     = (const float*)d_in[11];
    const float* weight_w   = (const float*)d_in[12];
    const float* out_w      = (const float*)d_in[13];
    const float* out_b      = (const float*)d_in[14];
    const float* context_w  = (const float*)d_in[15];
    const float* key_w      = (const float*)d_in[16];
    const float* logit_bias = (const float*)d_in[17];

    float* hbuf = (float*)d_ws;                       // B*N*E floats = 1 MB
    float* qk   = hbuf + (size_t)BB * NN * EE;        // B*E floats

    dim3 grid_rows(NN, BB, 1);
    k_rows<<<grid_rows, 512, 0, stream>>>(nf, ef, W, assigned, open_group,
        action_mask, build_limit, og_size, embed_w, embed_b, node_w, edge_w,
        weight_w, out_w, out_b, hbuf);

    k_ctx<<<BB, 512, 0, stream>>>(hbuf, open_group, context_w, key_w, qk);

    k_logits<<<BB * NN, 64, 0, stream>>>(hbuf, qk, action_mask, logit_bias,
        (float*)d_out);
}